// Round 1
// baseline (12.268 us; speedup 1.0000x reference)
//
#include <hip/hip_runtime.h>
#include <math.h>

#define IMG_SIZE 512
#define THRESH 160.0f

// One thread per sample. Walk r = 0..511 with early exit at the first pixel
// below THRESH; result is the running min distance up to and including that
// step. Arithmetic is kept faithful-f32 (no FMA contraction, libm sin/cos)
// so pixel-index decisions match the numpy reference as closely as possible.
__global__ __launch_bounds__(64) void euclid_loss_kernel(
    const float* __restrict__ coef,   // [B, 4]
    const float* __restrict__ image,  // [512, 512] row-major
    float* __restrict__ out,          // [B]
    int B)
{
    int b = blockIdx.x * blockDim.x + threadIdx.x;
    if (b >= B) return;

    const float4 c = reinterpret_cast<const float4*>(coef)[b];

    float runmin = INFINITY;
    #pragma unroll 1
    for (int ri = 0; ri < IMG_SIZE; ++ri) {
        const float r  = (float)ri;
        const float r2 = __fmul_rn(r, r);          // exact (511^2 < 2^24)
        const float r3 = __fmul_rn(r2, r);         // single rounding == powf

        // theta = c0 + c1*r + c2*r^2 + c3*r^3, sequential f32, no FMA,
        // einsum accumulation order d = 0..3 (0**0 == 1 handled by c0 term).
        float theta = c.x;
        theta = __fadd_rn(theta, __fmul_rn(c.y, r));
        theta = __fadd_rn(theta, __fmul_rn(c.z, r2));
        theta = __fadd_rn(theta, __fmul_rn(c.w, r3));

        const float ct = cosf(theta);              // accurate ocml, ~1 ulp
        const float st = sinf(theta);

        const float x = __fadd_rn(256.0f, __fmul_rn(r, ct));
        const float y = __fadd_rn(256.0f, __fmul_rn(r, st));

        const float dx = __fsub_rn(x, 400.0f);
        const float dy = __fsub_rn(y, 300.0f);
        const float dist =
            sqrtf(__fadd_rn(__fmul_rn(dx, dx), __fmul_rn(dy, dy)));

        runmin = fminf(runmin, dist);              // update min BEFORE exit test

        int xi = (int)x;                           // trunc toward zero
        int yi = (int)y;
        xi = max(0, min(IMG_SIZE - 1, xi));
        yi = max(0, min(IMG_SIZE - 1, yi));

        if (image[xi * IMG_SIZE + yi] < THRESH) break;
    }

    out[b] = runmin;
}

extern "C" void kernel_launch(void* const* d_in, const int* in_sizes, int n_in,
                              void* d_out, int out_size, void* d_ws, size_t ws_size,
                              hipStream_t stream) {
    const float* coef  = (const float*)d_in[0];   // [B,4] float32
    const float* image = (const float*)d_in[1];   // [512,512] float32
    float* out = (float*)d_out;                   // [B] float32

    const int B = in_sizes[0] / 4;
    const int block = 64;
    const int grid  = (B + block - 1) / block;
    euclid_loss_kernel<<<grid, block, 0, stream>>>(coef, image, out, B);
}

// Round 2
// 9.354 us; speedup vs baseline: 1.3115x; 1.3115x over previous
//
#include <hip/hip_runtime.h>
#include <math.h>

#define IMG_SIZE 512
#define THRESH 160.0f
#define CHUNK 8

// One thread per sample. Steps are independent except for the first-hit scan,
// so evaluate CHUNK steps speculatively: compute 8 thetas/sincos, issue all 8
// image loads (latencies overlap), then scan in order for the exit. Arithmetic
// per step is bit-identical to the serial version (no FMA, ocml sin/cos,
// trunc casts) so outputs remain exact vs the numpy reference.
__global__ __launch_bounds__(64) void euclid_loss_kernel(
    const float* __restrict__ coef,   // [B, 4]
    const float* __restrict__ image,  // [512, 512] row-major
    float* __restrict__ out,          // [B]
    int B)
{
    int b = blockIdx.x * blockDim.x + threadIdx.x;
    if (b >= B) return;

    const float4 c = reinterpret_cast<const float4*>(coef)[b];

    float runmin = INFINITY;
    bool done = false;

    for (int base = 0; base < IMG_SIZE && !done; base += CHUNK) {
        float dist[CHUNK];
        float px[CHUNK];

        #pragma unroll
        for (int k = 0; k < CHUNK; ++k) {
            const float r  = (float)(base + k);
            const float r2 = __fmul_rn(r, r);          // exact below 2^24
            const float r3 = __fmul_rn(r2, r);         // single rounding == powf

            float theta = c.x;
            theta = __fadd_rn(theta, __fmul_rn(c.y, r));
            theta = __fadd_rn(theta, __fmul_rn(c.z, r2));
            theta = __fadd_rn(theta, __fmul_rn(c.w, r3));

            const float ct = cosf(theta);              // accurate ocml
            const float st = sinf(theta);

            const float x = __fadd_rn(256.0f, __fmul_rn(r, ct));
            const float y = __fadd_rn(256.0f, __fmul_rn(r, st));

            const float dx = __fsub_rn(x, 400.0f);
            const float dy = __fsub_rn(y, 300.0f);
            dist[k] = sqrtf(__fadd_rn(__fmul_rn(dx, dx), __fmul_rn(dy, dy)));

            int xi = (int)x;                           // trunc toward zero
            int yi = (int)y;
            xi = max(0, min(IMG_SIZE - 1, xi));
            yi = max(0, min(IMG_SIZE - 1, yi));
            px[k] = image[xi * IMG_SIZE + yi];         // issued per k; waits
        }                                              // coalesce before use

        #pragma unroll
        for (int k = 0; k < CHUNK; ++k) {
            if (!done) {
                runmin = fminf(runmin, dist[k]);       // min BEFORE exit test
                if (px[k] < THRESH) done = true;
            }
        }
    }

    out[b] = runmin;
}

extern "C" void kernel_launch(void* const* d_in, const int* in_sizes, int n_in,
                              void* d_out, int out_size, void* d_ws, size_t ws_size,
                              hipStream_t stream) {
    const float* coef  = (const float*)d_in[0];   // [B,4] float32
    const float* image = (const float*)d_in[1];   // [512,512] float32
    float* out = (float*)d_out;                   // [B] float32

    const int B = in_sizes[0] / 4;
    const int block = 64;
    const int grid  = (B + block - 1) / block;
    euclid_loss_kernel<<<grid, block, 0, stream>>>(coef, image, out, B);
}